// Round 1
// baseline (516.385 us; speedup 1.0000x reference)
//
#include <hip/hip_runtime.h>

// Multi-head Hyena conv, attention-form restructure:
//   out[b,h*8+d2,l] = sum_{m<=l} k[h,l-m] * x2[b,h*8+d2,m] * s[l,m]
//                     + x2[b,h*8+d2,l] * sum_d1 bias[h*8+d1]*x1[d1,l]*v[d1,l]
//   s[l,m] = sum_d1 x1[b,h*8+d1,l] * v[b,h*8+d1,m]
// Shapes (fixed by setup): B=2, D=1024, L=2048, NH=8, H=128.

#define NHd   8
#define BLt   256   // l-tile per block == blockDim.x (thread <-> l)
#define BMt   128   // m-tile staged in LDS per iteration
#define MAXL  2048

__global__ __launch_bounds__(BLt, 4) void hyena_conv_kernel(
    const float* __restrict__ v, const float* __restrict__ kf,
    const float* __restrict__ bias, const float* __restrict__ x1,
    const float* __restrict__ x2, float* __restrict__ out,
    int B, int H, int L, int D)
{
    __shared__ float ks[MAXL];        // k[h, 0 .. l0+BLt)
    __shared__ float Ws[16][BMt];     // rows 0..7 = V[d1][m], rows 8..15 = X2[d2][m]

    const int bh  = blockIdx.x;
    const int b   = bh / H;
    const int h   = bh - b * H;
    const int l0  = blockIdx.y * BLt;
    const int tid = threadIdx.x;
    const int l   = l0 + tid;

    // stage k prefix into LDS (coalesced)
    const int kl = l0 + BLt;          // need k[0 .. max(l-m)] = k[0 .. l0+BLt-1]
    for (int i = tid; i < kl; i += BLt) ks[i] = kf[h * L + i];

    const int base = (b * D + h * NHd) * L;

    // per-thread x1 gate for own l (coalesced across lanes)
    float x1r[NHd];
#pragma unroll
    for (int d1 = 0; d1 < NHd; ++d1) x1r[d1] = x1[base + d1 * L + l];

    float acc[NHd];
#pragma unroll
    for (int d2 = 0; d2 < NHd; ++d2) acc[d2] = 0.f;

    const int mEnd = l0 + BLt;        // max m = max l within this block
    for (int m0 = 0; m0 < mEnd; m0 += BMt) {
        __syncthreads();
        {   // cooperative stage of V/X2 tile: 16 rows x BMt floats, [j][m] layout,
            // coalesced global reads (each 16-thread group covers one row)
            const int j  = tid >> 4;                 // 0..15
            const int ms = (tid & 15) * (BMt / 16);  // 8 m's per thread
            const float* src = (j < NHd)
                ? (v  + base + j          * L + m0 + ms)
                : (x2 + base + (j - NHd)  * L + m0 + ms);
            const float4 p0 = ((const float4*)src)[0];
            const float4 p1 = ((const float4*)src)[1];
            float* w = &Ws[j][ms];
            w[0] = p0.x; w[1] = p0.y; w[2] = p0.z; w[3] = p0.w;
            w[4] = p1.x; w[5] = p1.y; w[6] = p1.z; w[7] = p1.w;
        }
        __syncthreads();

        if (m0 + BMt <= l0) {
            // full tile: every m < l0 <= l, no causal mask needed
            for (int mm = 0; mm < BMt; mm += 4) {
                float4 col[NHd];                     // wave-uniform b128 broadcasts
#pragma unroll
                for (int d1 = 0; d1 < NHd; ++d1)
                    col[d1] = *(const float4*)&Ws[d1][mm];
                float s0 = 0.f, s1 = 0.f, s2 = 0.f, s3 = 0.f;
#pragma unroll
                for (int d1 = 0; d1 < NHd; ++d1) {
                    s0 += x1r[d1] * col[d1].x;
                    s1 += x1r[d1] * col[d1].y;
                    s2 += x1r[d1] * col[d1].z;
                    s3 += x1r[d1] * col[d1].w;
                }
                const int mb = m0 + mm;              // k reads: stride-1 per lane
                s0 *= ks[l - mb];
                s1 *= ks[l - mb - 1];
                s2 *= ks[l - mb - 2];
                s3 *= ks[l - mb - 3];
                float4 c2[NHd];
#pragma unroll
                for (int d2 = 0; d2 < NHd; ++d2)
                    c2[d2] = *(const float4*)&Ws[NHd + d2][mm];
#pragma unroll
                for (int d2 = 0; d2 < NHd; ++d2)
                    acc[d2] += s0 * c2[d2].x + s1 * c2[d2].y
                             + s2 * c2[d2].z + s3 * c2[d2].w;
            }
        } else {
            // diagonal tile: causal mask m <= l (<=2 such tiles per block)
            for (int mm = 0; mm < BMt; ++mm) {
                const int m   = m0 + mm;
                const float msk = (m <= l) ? 1.f : 0.f;
                const int ki  = (l - m) >= 0 ? (l - m) : 0;   // clamp: safe LDS read
                float s = 0.f;
#pragma unroll
                for (int d1 = 0; d1 < NHd; ++d1) s += x1r[d1] * Ws[d1][mm];
                const float t = s * ks[ki] * msk;
#pragma unroll
                for (int d2 = 0; d2 < NHd; ++d2) acc[d2] += t * Ws[NHd + d2][mm];
            }
        }
    }

    // skip term: x2[d2,l] * sum_d1 bias[h,d1]*x1[d1,l]*v[d1,l]; then store
    float sb = 0.f;
#pragma unroll
    for (int d1 = 0; d1 < NHd; ++d1)
        sb += bias[h * NHd + d1] * x1r[d1] * v[base + d1 * L + l];
#pragma unroll
    for (int d2 = 0; d2 < NHd; ++d2)
        out[base + d2 * L + l] = acc[d2] + x2[base + d2 * L + l] * sb;
}

extern "C" void kernel_launch(void* const* d_in, const int* in_sizes, int n_in,
                              void* d_out, int out_size, void* d_ws, size_t ws_size,
                              hipStream_t stream) {
    const float* v    = (const float*)d_in[0];
    const float* k    = (const float*)d_in[1];
    const float* bias = (const float*)d_in[2];
    const float* x1   = (const float*)d_in[3];
    const float* x2   = (const float*)d_in[4];
    float* out = (float*)d_out;

    const int D = in_sizes[2];            // 1024
    const int H = D / NHd;                // 128 (num_heads=8 fixed by setup)
    const int L = in_sizes[1] / H;        // 2048
    const int B = in_sizes[0] / (D * L);  // 2

    dim3 grid(B * H, L / BLt);
    hyena_conv_kernel<<<grid, BLt, 0, stream>>>(v, k, bias, x1, x2, out, B, H, L, D);
}

// Round 2
// 301.457 us; speedup vs baseline: 1.7130x; 1.7130x over previous
//
#include <hip/hip_runtime.h>
#include <hip/hip_bf16.h>

// Multi-head Hyena conv via MFMA (flash-attention-shaped):
//   S^T[m][l] = sum_d1 v[d1,m] * x1[d1,l]          (mfma1: M=m, N=l, K=d1 (8 of 32))
//   P[l][m]   = S[l,m] * kpad[KPAD + l - m]        (zero-pad => causal mask for free)
//   O[l][d2] += sum_m P[l][m] * x2[d2,m]           (mfma2: M=l, N=d2 (8 of 16), K=m)
//   out      = O + x2[d2,l] * sum_d1 bias*x1*v     (skip term, fp32)
// Shapes fixed by setup: B=2, D=1024, L=2048, NH=8, H=128.

typedef __attribute__((ext_vector_type(8))) short bf16x8;
typedef __attribute__((ext_vector_type(4))) float f32x4;

#define NHd   8
#define BL    64     // l per block (4 waves x 16)
#define WL    16     // l per wave (MFMA N)
#define SC    128    // m superchunk staged in LDS
#define CH    16     // m chunk per MFMA pass
#define KPAD  32     // zero pad in front of k => causal gate

static __device__ __forceinline__ ushort f2bf(float f) {
    union { __hip_bfloat16 h; ushort u; } c;
    c.h = __float2bfloat16(f);
    return c.u;
}

__global__ __launch_bounds__(256, 3) void hyena_mfma_kernel(
    const float* __restrict__ v, const float* __restrict__ kf,
    const float* __restrict__ bias, const float* __restrict__ x1,
    const float* __restrict__ x2, float* __restrict__ out,
    int B, int H, int L)
{
    __shared__ __align__(16) float  ks[KPAD + 2048];     // [0..KPAD)=0, then k[h,:]
    __shared__ __align__(16) ushort vT[SC][NHd];         // [m][d1] bf16
    __shared__ __align__(16) ushort x2T[NHd][SC + 8];    // [d2][m] bf16, padded row
    __shared__ __align__(16) ushort Pl[4][WL][CH];       // per-wave P [l][m] bf16
    __shared__ __align__(16) ushort x1T[BL][NHd];        // [l][d1] bf16
    __shared__ float sbuf[BL];                           // skip-term gate per l

    const int tid  = threadIdx.x;
    const int bh   = blockIdx.x;
    const int b    = bh / H, h = bh - b * H;
    const int l0b  = ((int)gridDim.y - 1 - (int)blockIdx.y) * BL;  // big blocks first
    const int base = (b * H + h) * NHd * L;

    const int lane = tid & 63;
    const int wv   = tid >> 6;        // wave id 0..3
    const int lq   = lane & 15;       // C-layout column / frag row index
    const int quad = lane >> 4;       // 0..3
    const int l0w  = l0b + wv * WL;

    // ---- prologue staging ----
    const int nk = l0b + BL;          // k prefix needed: k[0 .. nk)
    for (int i = tid; i < KPAD + nk; i += 256)
        ks[i] = (i < KPAD) ? 0.f : kf[h * L + i - KPAD];
    for (int i = tid; i < BL * NHd; i += 256) {
        const int l = i & (BL - 1), d1 = i >> 6;
        x1T[l][d1] = f2bf(x1[base + d1 * L + l0b + l]);
    }
    if (tid < BL) {
        float s = 0.f;
#pragma unroll
        for (int d1 = 0; d1 < NHd; ++d1)
            s += bias[h * NHd + d1] * x1[base + d1 * L + l0b + tid]
                                    * v [base + d1 * L + l0b + tid];
        sbuf[tid] = s;
    }
    __syncthreads();

    // B-operand of mfma1: x1^T[l][d1], loop-invariant per wave (quad0 holds k=0..7)
    bf16x8 xf = {};
    if (quad == 0) xf = *(const bf16x8*)&x1T[wv * WL + lq][0];

    f32x4 acc = {0.f, 0.f, 0.f, 0.f};

    for (int s0 = 0; s0 < nk; s0 += SC) {
        __syncthreads();
        {   // stage v^T [m][d1] and x2^T [d2][m] for this superchunk (bf16)
            const int d  = tid >> 5;            // 0..7
            const int mq = (tid & 31) * 4;      // 0..124
            const float4 pv = *(const float4*)&v [base + d * L + s0 + mq];
            const float4 px = *(const float4*)&x2[base + d * L + s0 + mq];
            vT[mq + 0][d] = f2bf(pv.x); vT[mq + 1][d] = f2bf(pv.y);
            vT[mq + 2][d] = f2bf(pv.z); vT[mq + 3][d] = f2bf(pv.w);
            ushort4 w;
            w.x = f2bf(px.x); w.y = f2bf(px.y); w.z = f2bf(px.z); w.w = f2bf(px.w);
            *(ushort4*)&x2T[d][mq] = w;
        }
        __syncthreads();

        for (int c = 0; c < SC; c += CH) {
            const int m0 = s0 + c;
            if (m0 > l0w + WL - 1) break;       // causal: wave-uniform

            // mfma1: S^T[m][l], A = v^T (quad0 carries d1=0..7, rest zero)
            bf16x8 av = {};
            if (quad == 0) av = *(const bf16x8*)&vT[c + lq][0];
            f32x4 S = __builtin_amdgcn_mfma_f32_16x16x32_bf16(
                av, xf, (f32x4){0.f, 0.f, 0.f, 0.f}, 0, 0, 0);

            // gate by k[l-m]; C-layout: lane holds m = quad*4+r, l = l0w+lq.
            // zero-pad in ks handles m > l exactly (gate reads 0).
            const int kb = KPAD + l0w + lq - m0 - quad * 4;
            ushort4 pw;
            pw.x = f2bf(S[0] * ks[kb    ]);
            pw.y = f2bf(S[1] * ks[kb - 1]);
            pw.z = f2bf(S[2] * ks[kb - 2]);
            pw.w = f2bf(S[3] * ks[kb - 3]);
            *(ushort4*)&Pl[wv][lq][quad * 4] = pw;   // P[l][m], 4 consec m

            // mfma2: O[l][d2] += P · x2^T  (K=32, valid k<16, upper half A=0)
            bf16x8 ap = {};
            if (quad < 2) ap = *(const bf16x8*)&Pl[wv][lq][quad * 8];
            const bf16x8 bx =
                *(const bf16x8*)&x2T[lane & 7][c + ((lane >> 4) & 1) * 8];
            acc = __builtin_amdgcn_mfma_f32_16x16x32_bf16(ap, bx, acc, 0, 0, 0);
        }
    }

    // ---- epilogue: skip term + store. D-layout: row(l)=quad*4+r, col(d2)=lq ----
    if (lq < NHd) {
        const int le = l0w + quad * 4;
        const float* x2p = &x2[base + lq * L + le];
        float*       op  = &out[base + lq * L + le];
#pragma unroll
        for (int r = 0; r < 4; ++r)
            op[r] = acc[r] + x2p[r] * sbuf[le - l0b + r - (l0b ? 0 : 0)]
                  - 0.f,
            op[r] = acc[r] + x2p[r] * sbuf[wv * WL + quad * 4 + r];
    }
}

extern "C" void kernel_launch(void* const* d_in, const int* in_sizes, int n_in,
                              void* d_out, int out_size, void* d_ws, size_t ws_size,
                              hipStream_t stream) {
    const float* v    = (const float*)d_in[0];
    const float* k    = (const float*)d_in[1];
    const float* bias = (const float*)d_in[2];
    const float* x1   = (const float*)d_in[3];
    const float* x2   = (const float*)d_in[4];
    float* out = (float*)d_out;

    const int D = in_sizes[2];            // 1024
    const int H = D / NHd;                // 128
    const int L = in_sizes[1] / H;        // 2048
    const int B = in_sizes[0] / (D * L);  // 2

    dim3 grid(B * H, L / BL);
    hyena_mfma_kernel<<<grid, 256, 0, stream>>>(v, k, bias, x1, x2, out, B, H, L);
}

// Round 3
// 228.158 us; speedup vs baseline: 2.2633x; 1.3213x over previous
//
#include <hip/hip_runtime.h>
#include <hip/hip_bf16.h>
#include <stdint.h>

// Multi-head Hyena conv, MFMA flash-attention form, round 3:
//   S^T[m][l] = sum_d1 v[d1,m]*x1[d1,l]      mfma 16x16x32 (K=8 valid)
//   P[l][m]   = S * k[l-m]  (packed bf16 gate table, zero-pad => causal)
//   O[l][d2] += P · x2^T                     mfma 16x16x32 (full K=32)
// Block: 256 thr = 4 waves, covers (h, 64 l, both b). Wave: b=wv>>1, 32 l.

typedef __attribute__((ext_vector_type(8))) short bf16x8;
typedef __attribute__((ext_vector_type(4))) float f32x4;

#define NHd  8
#define KOFF 32      // zero entries in front of gate table (causality)
#define SC   128     // m superchunk staged in LDS
#define PLD  40      // Pl row stride in ushorts (20 dwords: conflict-friendly)

static __device__ __forceinline__ ushort f2bf(float f) {
    union { __hip_bfloat16 h; ushort u; } c;
    c.h = __float2bfloat16(f);
    return c.u;
}
static __device__ __forceinline__ float bf2f(ushort u) {
    union { float f; uint32_t u; } c;
    c.u = ((uint32_t)u) << 16;
    return c.f;
}

__global__ __launch_bounds__(256, 4) void hyena_mfma3_kernel(
    const float* __restrict__ v, const float* __restrict__ kf,
    const float* __restrict__ bias, const float* __restrict__ x1,
    const float* __restrict__ x2, float* __restrict__ out,
    int B, int H, int L)
{
    __shared__ __align__(16) uint64_t ksp[KOFF + 2048];   // packed 4xbf16 gates
    __shared__ __align__(16) ushort vT[2][SC][NHd];       // [b][m][d1]
    __shared__ __align__(16) ushort x1T[2][64][NHd];      // [b][l][d1]
    __shared__ __align__(16) ushort Pl[4][2][16][PLD];    // per-wave, per-subtile
    __shared__ float sbuf[2][64];                         // skip gate per (b,l)

    const int tid  = threadIdx.x;
    const int h    = blockIdx.x;
    const int l0b  = ((int)gridDim.y - 1 - (int)blockIdx.y) * 64;  // big-l first
    const int nk   = l0b + 64;

    const int lane = tid & 63, wv = tid >> 6;
    const int lq   = lane & 15, quad = lane >> 4;
    const int wb   = wv >> 1;               // batch handled by this wave
    const int wl0  = l0b + (wv & 1) * 32;   // wave's 32-l range start
    const int D    = H * NHd;

    // ---------- prologue ----------
    // gate table: ksp[KOFF+i] packs bf16(k[i-r]) in half r (r=0..3); i<0 -> 0
    for (int i = tid; i < KOFF; i += 256) ksp[i] = 0ULL;
    for (int i = tid; i < nk; i += 256) {
        const float* kp = kf + h * L;
        uint64_t w = (uint64_t)f2bf(kp[i]);
        if (i >= 1) w |= (uint64_t)f2bf(kp[i - 1]) << 16;
        if (i >= 2) w |= (uint64_t)f2bf(kp[i - 2]) << 32;
        if (i >= 3) w |= (uint64_t)f2bf(kp[i - 3]) << 48;
        ksp[KOFF + i] = w;
    }
    // x1T (bf16) + skip-term gate, both b (threads 0..127)
    if (tid < 128) {
        const int bb = tid >> 6, l = tid & 63;
        const int bs = (bb * H + h) * NHd * L;
        float s = 0.f;
        ushort tmp[NHd];
#pragma unroll
        for (int d1 = 0; d1 < NHd; ++d1) {
            const float xv = x1[bs + d1 * L + l0b + l];
            tmp[d1] = f2bf(xv);
            s += bias[h * NHd + d1] * xv * v[bs + d1 * L + l0b + l];
        }
        *(bf16x8*)&x1T[bb][l][0] = *(bf16x8*)tmp;
        sbuf[bb][l] = s;
    }
    __syncthreads();

    const int baseb = (wb * H + h) * NHd * L;
    const float* x2w = x2 + baseb + (lq & 7) * L;   // d2-row for B-frag & epilogue

    // mfma1 B operand (x1 fragments), loop-invariant
    bf16x8 xf0 = {}, xf1 = {};
    if (quad == 0) {
        xf0 = *(const bf16x8*)&x1T[wb][wl0 - l0b + lq][0];
        xf1 = *(const bf16x8*)&x1T[wb][wl0 - l0b + 16 + lq][0];
    }

    f32x4 acc0 = {0.f, 0.f, 0.f, 0.f}, acc1 = {0.f, 0.f, 0.f, 0.f};
    const int wlmax = wl0 + 31;

    for (int s0 = 0; s0 < nk; s0 += SC) {
        __syncthreads();
        {   // stage vT: thread = (b, m-row); 8 coalesced dwords -> one b128 write
            const int bb = tid >> 7, row = tid & 127;
            const float* vp = v + (bb * H + h) * NHd * L + s0 + row;
            ushort tmp[NHd];
#pragma unroll
            for (int d1 = 0; d1 < NHd; ++d1) tmp[d1] = f2bf(vp[d1 * L]);
            *(bf16x8*)&vT[bb][row][0] = *(bf16x8*)tmp;
        }
        __syncthreads();

        const int cmax = min(SC, wlmax - s0 + 1);   // wave-uniform, mult of 32
        for (int c = 0; c < cmax; c += 32) {
            const int m0 = s0 + c;

            // ---- loads first (independent) ----
            bf16x8 av0 = {}, av1 = {};
            if (quad == 0) {
                av0 = *(const bf16x8*)&vT[wb][c + lq][0];
                av1 = *(const bf16x8*)&vT[wb][c + 16 + lq][0];
            }
            const int gb = KOFF + lq - 4 * quad - m0;
            const uint64_t g00 = ksp[gb + wl0];        // t0/chunk0 == t1/chunk1
            const uint64_t g01 = ksp[gb + wl0 - 16];   // t0/chunk1
            const uint64_t g10 = ksp[gb + wl0 + 16];   // t1/chunk0
            // B-frag of mfma2 from global f32 (vmem pipe), cvt to bf16
            const float4 ba = *(const float4*)(x2w + m0 + quad * 8);
            const float4 bb4 = *(const float4*)(x2w + m0 + quad * 8 + 4);
            ushort bxa[8];
            bxa[0] = f2bf(ba.x);  bxa[1] = f2bf(ba.y);
            bxa[2] = f2bf(ba.z);  bxa[3] = f2bf(ba.w);
            bxa[4] = f2bf(bb4.x); bxa[5] = f2bf(bb4.y);
            bxa[6] = f2bf(bb4.z); bxa[7] = f2bf(bb4.w);
            const bf16x8 bx = *(const bf16x8*)bxa;

            // ---- mfma1 x4: S^T for 2 m-chunks x 2 l-subtiles ----
            const f32x4 Z = {0.f, 0.f, 0.f, 0.f};
            const f32x4 S00 = __builtin_amdgcn_mfma_f32_16x16x32_bf16(av0, xf0, Z, 0, 0, 0);
            const f32x4 S01 = __builtin_amdgcn_mfma_f32_16x16x32_bf16(av1, xf0, Z, 0, 0, 0);
            const f32x4 S10 = __builtin_amdgcn_mfma_f32_16x16x32_bf16(av0, xf1, Z, 0, 0, 0);
            const f32x4 S11 = __builtin_amdgcn_mfma_f32_16x16x32_bf16(av1, xf1, Z, 0, 0, 0);

            // ---- gate + pack + P round-trip, sub-tile 0 ----
            uint64_t w0 = 0, w1 = 0;
#pragma unroll
            for (int r = 0; r < 4; ++r) {
                w0 |= (uint64_t)f2bf(S00[r] * bf2f((ushort)(g00 >> (16 * r)))) << (16 * r);
                w1 |= (uint64_t)f2bf(S01[r] * bf2f((ushort)(g01 >> (16 * r)))) << (16 * r);
            }
            *(uint64_t*)&Pl[wv][0][lq][quad * 4]      = w0;
            *(uint64_t*)&Pl[wv][0][lq][16 + quad * 4] = w1;
            // sub-tile 1 (chunk1 gate == g00)
            uint64_t w2 = 0, w3 = 0;
#pragma unroll
            for (int r = 0; r < 4; ++r) {
                w2 |= (uint64_t)f2bf(S10[r] * bf2f((ushort)(g10 >> (16 * r)))) << (16 * r);
                w3 |= (uint64_t)f2bf(S11[r] * bf2f((ushort)(g00 >> (16 * r)))) << (16 * r);
            }
            *(uint64_t*)&Pl[wv][1][lq][quad * 4]      = w2;
            *(uint64_t*)&Pl[wv][1][lq][16 + quad * 4] = w3;

            // ---- mfma2: full K=32 ----
            const bf16x8 ap0 = *(const bf16x8*)&Pl[wv][0][lq][quad * 8];
            acc0 = __builtin_amdgcn_mfma_f32_16x16x32_bf16(ap0, bx, acc0, 0, 0, 0);
            const bf16x8 ap1 = *(const bf16x8*)&Pl[wv][1][lq][quad * 8];
            acc1 = __builtin_amdgcn_mfma_f32_16x16x32_bf16(ap1, bx, acc1, 0, 0, 0);
        }
    }

    // ---------- epilogue: + x2[d2,l]*skip, store float4 ----------
    if (lq < NHd) {
        const int lloc = (wv & 1) * 32 + quad * 4;    // l offset within block
        const float* xr = x2w + wl0 + quad * 4;
        float* orow = out + baseb + lq * L + wl0 + quad * 4;
        float4 o0, o1;
        o0.x = acc0[0] + xr[0] * sbuf[wb][lloc + 0];
        o0.y = acc0[1] + xr[1] * sbuf[wb][lloc + 1];
        o0.z = acc0[2] + xr[2] * sbuf[wb][lloc + 2];
        o0.w = acc0[3] + xr[3] * sbuf[wb][lloc + 3];
        o1.x = acc1[0] + xr[16] * sbuf[wb][lloc + 16];
        o1.y = acc1[1] + xr[17] * sbuf[wb][lloc + 17];
        o1.z = acc1[2] + xr[18] * sbuf[wb][lloc + 18];
        o1.w = acc1[3] + xr[19] * sbuf[wb][lloc + 19];
        *(float4*)orow = o0;
        *(float4*)(orow + 16) = o1;
    }
}

extern "C" void kernel_launch(void* const* d_in, const int* in_sizes, int n_in,
                              void* d_out, int out_size, void* d_ws, size_t ws_size,
                              hipStream_t stream) {
    const float* v    = (const float*)d_in[0];
    const float* k    = (const float*)d_in[1];
    const float* bias = (const float*)d_in[2];
    const float* x1   = (const float*)d_in[3];
    const float* x2   = (const float*)d_in[4];
    float* out = (float*)d_out;

    const int D = in_sizes[2];            // 1024
    const int H = D / NHd;                // 128
    const int L = in_sizes[1] / H;        // 2048
    const int B = in_sizes[0] / (D * L);  // 2

    dim3 grid(H, L / 64);
    hyena_mfma3_kernel<<<grid, 256, 0, stream>>>(v, k, bias, x1, x2, out, B, H, L);
}

// Round 4
// 191.197 us; speedup vs baseline: 2.7008x; 1.1933x over previous
//
#include <hip/hip_runtime.h>
#include <stdint.h>

// Multi-head Hyena conv, MFMA flash-attention form, round 4:
//   S^T[m][l] = sum_d1 v[d1,m]*x1[d1,l]      mfma 16x16x32 (K=8 valid)
//   P[l][m]   = S * k[l-m]  (f32x4 gate table, zero-pad => causal)
//   O[l][d2] += P . x2^T                     mfma 16x16x32 (full K=32)
// Round-4 changes: f32x4 gate table (no shifts), v_perm bf16 packing,
// x2 B-frags staged in LDS, xf in registers, 3 blocks/CU.
// Shapes fixed by setup: B=2, D=1024, L=2048, NH=8, H=128.

typedef __attribute__((ext_vector_type(8))) short bf16x8;
typedef __attribute__((ext_vector_type(4))) float f32x4;

#define NHd  8
#define KOFF 48      // zero f32x4 entries in front of gate table (causality)
#define SC   128     // m superchunk staged in LDS
#define PLS  40      // Pl row stride in ushorts (80 B: 16B-aligned, 2-way banks)

static __device__ __forceinline__ uint32_t pkbf(float a, float b) {
    // pack {bf16(a) lo, bf16(b) hi}; +0x8000 = round-to-nearest (ties away)
    const uint32_t ua = __float_as_uint(a) + 0x8000u;
    const uint32_t ub = __float_as_uint(b) + 0x8000u;
    return __builtin_amdgcn_perm(ub, ua, 0x07060302u);
}

union U8 { uint32_t u[4]; bf16x8 v; uint4 q; };

__global__ __launch_bounds__(256, 3) void hyena_mfma4_kernel(
    const float* __restrict__ v, const float* __restrict__ kf,
    const float* __restrict__ bias, const float* __restrict__ x1,
    const float* __restrict__ x2, float* __restrict__ out,
    int B, int H, int L)
{
    __shared__ __align__(16) float4 gsp[KOFF + 2048];   // {k[i],k[i-1],k[i-2],k[i-3]}
    __shared__ __align__(16) ushort vT[2][SC][NHd];     // [b][m][d1] bf16
    __shared__ __align__(16) ushort x2T[2][NHd][136];   // [b][d2][m] bf16 (pad 8)
    __shared__ __align__(16) union {
        ushort Pl[4][2][16][PLS];                       // per-wave P round-trip
        float  ksf[2560];                               // prologue overlay: raw k
    } pool;
    __shared__ float sbuf[2][64];                       // skip gate per (b,l)

    const int tid  = threadIdx.x;
    const int h    = blockIdx.x;
    const int l0b  = ((int)gridDim.y - 1 - (int)blockIdx.y) * 64;  // big-l first
    const int nk   = l0b + 64;

    const int lane = tid & 63, wv = tid >> 6;
    const int lq   = lane & 15, quad = lane >> 4;
    const int wb   = wv >> 1;               // batch handled by this wave
    const int wl0  = l0b + (wv & 1) * 32;   // wave's 32-l range start
    const int baseb = (wb * H + h) * NHd * L;

    // ---------- prologue ----------
    // raw k -> ksf (overlay on Pl space)
    for (int i = tid; i < nk; i += 256) pool.ksf[i] = kf[h * L + i];

    // xf fragments (mfma1 B operand) straight from global, packed in registers
    bf16x8 xf0 = {}, xf1 = {};
    if (quad == 0) {
        float a0[NHd], a1[NHd];
#pragma unroll
        for (int d1 = 0; d1 < NHd; ++d1) {
            a0[d1] = x1[baseb + d1 * L + wl0 + lq];
            a1[d1] = x1[baseb + d1 * L + wl0 + 16 + lq];
        }
        U8 u0, u1;
#pragma unroll
        for (int j = 0; j < 4; ++j) {
            u0.u[j] = pkbf(a0[2 * j], a0[2 * j + 1]);
            u1.u[j] = pkbf(a1[2 * j], a1[2 * j + 1]);
        }
        xf0 = u0.v; xf1 = u1.v;
    }

    // skip-term gate, both b (threads 0..127)
    if (tid < 128) {
        const int bb = tid >> 6, l = tid & 63;
        const int bs = (bb * H + h) * NHd * L;
        float s = 0.f;
#pragma unroll
        for (int d1 = 0; d1 < NHd; ++d1)
            s += bias[h * NHd + d1] * x1[bs + d1 * L + l0b + l]
                                    * v [bs + d1 * L + l0b + l];
        sbuf[bb][l] = s;
    }
    __syncthreads();

    // build f32x4 gate table from ksf
    for (int e = tid; e < KOFF + nk; e += 256) {
        const int i = e - KOFF;
        float4 w = {0.f, 0.f, 0.f, 0.f};
        if (i >= 0) {
            w.x = pool.ksf[i];
            if (i >= 1) w.y = pool.ksf[i - 1];
            if (i >= 2) w.z = pool.ksf[i - 2];
            if (i >= 3) w.w = pool.ksf[i - 3];
        }
        gsp[e] = w;
    }

    f32x4 acc0 = {0.f, 0.f, 0.f, 0.f}, acc1 = {0.f, 0.f, 0.f, 0.f};
    const int wlmax = wl0 + 31;

    for (int s0 = 0; s0 < nk; s0 += SC) {
        __syncthreads();   // (first iter: also fences gsp build / ksf overlay)
        {   // stage vT [b][m][d1] and x2T [b][d2][m], bf16 via pkbf
            const int bb = tid >> 7, row = tid & 127;
            const int bs = (bb * H + h) * NHd * L;
            const float* vp = v + bs + s0 + row;
            float f[NHd];
#pragma unroll
            for (int d1 = 0; d1 < NHd; ++d1) f[d1] = vp[d1 * L];
            *(uint4*)&vT[bb][row][0] = make_uint4(
                pkbf(f[0], f[1]), pkbf(f[2], f[3]),
                pkbf(f[4], f[5]), pkbf(f[6], f[7]));

            const int d2 = row >> 4, ms = (row & 15) * 8;
            const float* xp = x2 + bs + d2 * L + s0 + ms;
            const float4 q0 = *(const float4*)xp;
            const float4 q1 = *(const float4*)(xp + 4);
            *(uint4*)&x2T[bb][d2][ms] = make_uint4(
                pkbf(q0.x, q0.y), pkbf(q0.z, q0.w),
                pkbf(q1.x, q1.y), pkbf(q1.z, q1.w));
        }
        __syncthreads();

        const int cmax = min(SC, wlmax - s0 + 1);   // wave-uniform, mult of 32
        for (int c = 0; c < cmax; c += 32) {
            const int m0 = s0 + c;

            // ---- loads first (independent) ----
            bf16x8 av0 = {}, av1 = {};
            if (quad == 0) {
                av0 = *(const bf16x8*)&vT[wb][c + lq][0];
                av1 = *(const bf16x8*)&vT[wb][c + 16 + lq][0];
            }
            const int ge = KOFF + wl0 + lq - 4 * quad - m0;
            const float4 g00 = *(const float4*)&gsp[ge];        // S00 & S11
            const float4 g01 = *(const float4*)&gsp[ge - 16];   // S01
            const float4 g10 = *(const float4*)&gsp[ge + 16];   // S10
            const bf16x8 bx = *(const bf16x8*)&x2T[wb][lq & 7][c + 8 * quad];

            // ---- mfma1 x4: S^T, 2 m-chunks x 2 l-subtiles ----
            const f32x4 Z = {0.f, 0.f, 0.f, 0.f};
            const f32x4 S00 = __builtin_amdgcn_mfma_f32_16x16x32_bf16(av0, xf0, Z, 0, 0, 0);
            const f32x4 S01 = __builtin_amdgcn_mfma_f32_16x16x32_bf16(av1, xf0, Z, 0, 0, 0);
            const f32x4 S10 = __builtin_amdgcn_mfma_f32_16x16x32_bf16(av0, xf1, Z, 0, 0, 0);
            const f32x4 S11 = __builtin_amdgcn_mfma_f32_16x16x32_bf16(av1, xf1, Z, 0, 0, 0);

            // ---- gate (f32 mul) + perm-pack + P round-trip ----
            uint2 w;
            w.x = pkbf(S00[0] * g00.x, S00[1] * g00.y);
            w.y = pkbf(S00[2] * g00.z, S00[3] * g00.w);
            *(uint2*)&pool.Pl[wv][0][lq][4 * quad] = w;
            w.x = pkbf(S01[0] * g01.x, S01[1] * g01.y);
            w.y = pkbf(S01[2] * g01.z, S01[3] * g01.w);
            *(uint2*)&pool.Pl[wv][0][lq][16 + 4 * quad] = w;
            w.x = pkbf(S10[0] * g10.x, S10[1] * g10.y);
            w.y = pkbf(S10[2] * g10.z, S10[3] * g10.w);
            *(uint2*)&pool.Pl[wv][1][lq][4 * quad] = w;
            w.x = pkbf(S11[0] * g00.x, S11[1] * g00.y);
            w.y = pkbf(S11[2] * g00.z, S11[3] * g00.w);
            *(uint2*)&pool.Pl[wv][1][lq][16 + 4 * quad] = w;

            // ---- mfma2: full K=32 ----
            const bf16x8 ap0 = *(const bf16x8*)&pool.Pl[wv][0][lq][8 * quad];
            acc0 = __builtin_amdgcn_mfma_f32_16x16x32_bf16(ap0, bx, acc0, 0, 0, 0);
            const bf16x8 ap1 = *(const bf16x8*)&pool.Pl[wv][1][lq][8 * quad];
            acc1 = __builtin_amdgcn_mfma_f32_16x16x32_bf16(ap1, bx, acc1, 0, 0, 0);
        }
    }

    // ---------- epilogue: + x2[d2,l]*skip, store float4 ----------
    if (lq < NHd) {
        const int lloc = (wv & 1) * 32 + quad * 4;    // l offset within block
        const float* xr = x2 + baseb + lq * L + wl0 + quad * 4;
        float* orow = out + baseb + lq * L + wl0 + quad * 4;
        float4 o0, o1;
        o0.x = acc0[0] + xr[0] * sbuf[wb][lloc + 0];
        o0.y = acc0[1] + xr[1] * sbuf[wb][lloc + 1];
        o0.z = acc0[2] + xr[2] * sbuf[wb][lloc + 2];
        o0.w = acc0[3] + xr[3] * sbuf[wb][lloc + 3];
        o1.x = acc1[0] + xr[16] * sbuf[wb][lloc + 16];
        o1.y = acc1[1] + xr[17] * sbuf[wb][lloc + 17];
        o1.z = acc1[2] + xr[18] * sbuf[wb][lloc + 18];
        o1.w = acc1[3] + xr[19] * sbuf[wb][lloc + 19];
        *(float4*)orow = o0;
        *(float4*)(orow + 16) = o1;
    }
}

extern "C" void kernel_launch(void* const* d_in, const int* in_sizes, int n_in,
                              void* d_out, int out_size, void* d_ws, size_t ws_size,
                              hipStream_t stream) {
    const float* v    = (const float*)d_in[0];
    const float* k    = (const float*)d_in[1];
    const float* bias = (const float*)d_in[2];
    const float* x1   = (const float*)d_in[3];
    const float* x2   = (const float*)d_in[4];
    float* out = (float*)d_out;

    const int D = in_sizes[2];            // 1024
    const int H = D / NHd;                // 128
    const int L = in_sizes[1] / H;        // 2048
    const int B = in_sizes[0] / (D * L);  // 2

    dim3 grid(H, L / 64);
    hyena_mfma4_kernel<<<grid, 256, 0, stream>>>(v, k, bias, x1, x2, out, B, H, L);
}

// Round 5
// 177.614 us; speedup vs baseline: 2.9073x; 1.0765x over previous
//
#include <hip/hip_runtime.h>
#include <stdint.h>

// Multi-head Hyena conv, MFMA flash-attention form, round 5:
//   S^T[m][l] = sum_d1 v[d1,m]*x1[d1,l]      mfma 16x16x32 (K=8 valid)
//   P[l][m]   = S * k[l-m]  (sliding f32x4 gate window, zero => causal)
//   O[l][d2] += P . x2^T                     mfma 16x16x32 (full K=32)
// Round-5 change: replace 32.7KB full gate table with 8KB raw k + 3KB
// sliding 192-entry window rebuilt per superchunk => LDS 52.7->30.5KB,
// 5 blocks/CU (was ~2.5). Everything else as round 4.
// Shapes fixed by setup: B=2, D=1024, L=2048, NH=8, H=128.

typedef __attribute__((ext_vector_type(8))) short bf16x8;
typedef __attribute__((ext_vector_type(4))) float f32x4;

#define NHd  8
#define SC   128     // m superchunk staged in LDS
#define PLS  40      // Pl row stride in ushorts (80 B: 16B-aligned, 2-way banks)
#define GW   192     // gate window entries: l-m spans [l0b-s0-127, l0b-s0+63]

static __device__ __forceinline__ uint32_t pkbf(float a, float b) {
    // pack {bf16(a) lo, bf16(b) hi}; +0x8000 = round-to-nearest (ties away)
    const uint32_t ua = __float_as_uint(a) + 0x8000u;
    const uint32_t ub = __float_as_uint(b) + 0x8000u;
    return __builtin_amdgcn_perm(ub, ua, 0x07060302u);
}

union U8 { uint32_t u[4]; bf16x8 v; uint4 q; };

__global__ __launch_bounds__(256, 5) void hyena_mfma5_kernel(
    const float* __restrict__ v, const float* __restrict__ kf,
    const float* __restrict__ bias, const float* __restrict__ x1,
    const float* __restrict__ x2, float* __restrict__ out,
    int B, int H, int L)
{
    __shared__ __align__(16) float  ks[2048];           // raw k[h,:] prefix
    __shared__ __align__(16) float4 gwin[GW];           // sliding gate window
    __shared__ __align__(16) ushort vT[2][SC][NHd];     // [b][m][d1] bf16
    __shared__ __align__(16) ushort x2T[2][NHd][136];   // [b][d2][m] bf16 (pad 8)
    __shared__ __align__(16) ushort Pl[4][2][16][PLS];  // per-wave P round-trip
    __shared__ float sbuf[2][64];                       // skip gate per (b,l)

    const int tid  = threadIdx.x;
    const int h    = blockIdx.x;
    const int l0b  = ((int)gridDim.y - 1 - (int)blockIdx.y) * 64;  // big-l first
    const int nk   = l0b + 64;

    const int lane = tid & 63, wv = tid >> 6;
    const int lq   = lane & 15, quad = lane >> 4;
    const int wb   = wv >> 1;               // batch handled by this wave
    const int wl0  = l0b + (wv & 1) * 32;   // wave's 32-l range start
    const int baseb = (wb * H + h) * NHd * L;

    // ---------- prologue ----------
    for (int i = tid; i < nk; i += 256) ks[i] = kf[h * L + i];

    // xf fragments (mfma1 B operand) straight from global, packed in registers
    bf16x8 xf0 = {}, xf1 = {};
    if (quad == 0) {
        float a0[NHd], a1[NHd];
#pragma unroll
        for (int d1 = 0; d1 < NHd; ++d1) {
            a0[d1] = x1[baseb + d1 * L + wl0 + lq];
            a1[d1] = x1[baseb + d1 * L + wl0 + 16 + lq];
        }
        U8 u0, u1;
#pragma unroll
        for (int j = 0; j < 4; ++j) {
            u0.u[j] = pkbf(a0[2 * j], a0[2 * j + 1]);
            u1.u[j] = pkbf(a1[2 * j], a1[2 * j + 1]);
        }
        xf0 = u0.v; xf1 = u1.v;
    }

    // skip-term gate, both b (threads 0..127)
    if (tid < 128) {
        const int bb = tid >> 6, l = tid & 63;
        const int bs = (bb * H + h) * NHd * L;
        float s = 0.f;
#pragma unroll
        for (int d1 = 0; d1 < NHd; ++d1)
            s += bias[h * NHd + d1] * x1[bs + d1 * L + l0b + l]
                                    * v [bs + d1 * L + l0b + l];
        sbuf[bb][l] = s;
    }

    f32x4 acc0 = {0.f, 0.f, 0.f, 0.f}, acc1 = {0.f, 0.f, 0.f, 0.f};
    const int wlmax = wl0 + 31;
    // in-loop gate window coordinate (s0-independent): e = ebase - c (+/-16)
    const int ebase = 127 + (wv & 1) * 32 + lq - 4 * quad;

    for (int s0 = 0; s0 < nk; s0 += SC) {
        __syncthreads();   // protects gwin/vT/x2T from previous iter's readers
        {   // stage vT [b][m][d1] and x2T [b][d2][m], bf16 via pkbf
            const int bb = tid >> 7, row = tid & 127;
            const int bs = (bb * H + h) * NHd * L;
            const float* vp = v + bs + s0 + row;
            float f[NHd];
#pragma unroll
            for (int d1 = 0; d1 < NHd; ++d1) f[d1] = vp[d1 * L];
            *(uint4*)&vT[bb][row][0] = make_uint4(
                pkbf(f[0], f[1]), pkbf(f[2], f[3]),
                pkbf(f[4], f[5]), pkbf(f[6], f[7]));

            const int d2 = row >> 4, ms = (row & 15) * 8;
            const float* xp = x2 + bs + d2 * L + s0 + ms;
            const float4 q0 = *(const float4*)xp;
            const float4 q1 = *(const float4*)(xp + 4);
            *(uint4*)&x2T[bb][d2][ms] = make_uint4(
                pkbf(q0.x, q0.y), pkbf(q0.z, q0.w),
                pkbf(q1.x, q1.y), pkbf(q1.z, q1.w));
        }
        // rebuild sliding gate window: gwin[e] = {k[i],k[i-1],k[i-2],k[i-3]},
        // i = l0b - s0 - 127 + e; i<0 components -> 0 (causality)
        if (tid < GW - 1) {
            const int i = l0b - s0 - 127 + tid;
            float4 w = {0.f, 0.f, 0.f, 0.f};
            if (i >= 3) {
                w.x = ks[i]; w.y = ks[i - 1]; w.z = ks[i - 2]; w.w = ks[i - 3];
            } else if (i >= 0) {
                w.x = ks[i];
                if (i >= 1) w.y = ks[i - 1];
                if (i >= 2) w.z = ks[i - 2];
            }
            gwin[tid] = w;
        }
        __syncthreads();

        const int cmax = min(SC, wlmax - s0 + 1);   // wave-uniform, mult of 32
        for (int c = 0; c < cmax; c += 32) {
            // ---- loads first (independent) ----
            bf16x8 av0 = {}, av1 = {};
            if (quad == 0) {
                av0 = *(const bf16x8*)&vT[wb][c + lq][0];
                av1 = *(const bf16x8*)&vT[wb][c + 16 + lq][0];
            }
            const int ge = ebase - c;
            const float4 g00 = *(const float4*)&gwin[ge];        // S00 & S11
            const float4 g01 = *(const float4*)&gwin[ge - 16];   // S01
            const float4 g10 = *(const float4*)&gwin[ge + 16];   // S10
            const bf16x8 bx = *(const bf16x8*)&x2T[wb][lq & 7][c + 8 * quad];

            // ---- mfma1 x4: S^T, 2 m-chunks x 2 l-subtiles ----
            const f32x4 Z = {0.f, 0.f, 0.f, 0.f};
            const f32x4 S00 = __builtin_amdgcn_mfma_f32_16x16x32_bf16(av0, xf0, Z, 0, 0, 0);
            const f32x4 S01 = __builtin_amdgcn_mfma_f32_16x16x32_bf16(av1, xf0, Z, 0, 0, 0);
            const f32x4 S10 = __builtin_amdgcn_mfma_f32_16x16x32_bf16(av0, xf1, Z, 0, 0, 0);
            const f32x4 S11 = __builtin_amdgcn_mfma_f32_16x16x32_bf16(av1, xf1, Z, 0, 0, 0);

            // ---- gate (f32 mul) + perm-pack + P round-trip ----
            uint2 w;
            w.x = pkbf(S00[0] * g00.x, S00[1] * g00.y);
            w.y = pkbf(S00[2] * g00.z, S00[3] * g00.w);
            *(uint2*)&Pl[wv][0][lq][4 * quad] = w;
            w.x = pkbf(S01[0] * g01.x, S01[1] * g01.y);
            w.y = pkbf(S01[2] * g01.z, S01[3] * g01.w);
            *(uint2*)&Pl[wv][0][lq][16 + 4 * quad] = w;
            w.x = pkbf(S10[0] * g10.x, S10[1] * g10.y);
            w.y = pkbf(S10[2] * g10.z, S10[3] * g10.w);
            *(uint2*)&Pl[wv][1][lq][4 * quad] = w;
            w.x = pkbf(S11[0] * g00.x, S11[1] * g00.y);
            w.y = pkbf(S11[2] * g00.z, S11[3] * g00.w);
            *(uint2*)&Pl[wv][1][lq][16 + 4 * quad] = w;

            // ---- mfma2: full K=32 ----
            const bf16x8 ap0 = *(const bf16x8*)&Pl[wv][0][lq][8 * quad];
            acc0 = __builtin_amdgcn_mfma_f32_16x16x32_bf16(ap0, bx, acc0, 0, 0, 0);
            const bf16x8 ap1 = *(const bf16x8*)&Pl[wv][1][lq][8 * quad];
            acc1 = __builtin_amdgcn_mfma_f32_16x16x32_bf16(ap1, bx, acc1, 0, 0, 0);
        }
    }

    // ---------- epilogue: + x2[d2,l]*skip, store float4 ----------
    if (lq < NHd) {
        const int lloc = (wv & 1) * 32 + quad * 4;    // l offset within block
        const float* xr = x2 + baseb + lq * L + wl0 + quad * 4;
        float* orow = out + baseb + lq * L + wl0 + quad * 4;
        float4 o0, o1;
        o0.x = acc0[0] + xr[0] * sbuf[wb][lloc + 0];
        o0.y = acc0[1] + xr[1] * sbuf[wb][lloc + 1];
        o0.z = acc0[2] + xr[2] * sbuf[wb][lloc + 2];
        o0.w = acc0[3] + xr[3] * sbuf[wb][lloc + 3];
        o1.x = acc1[0] + xr[16] * sbuf[wb][lloc + 16];
        o1.y = acc1[1] + xr[17] * sbuf[wb][lloc + 17];
        o1.z = acc1[2] + xr[18] * sbuf[wb][lloc + 18];
        o1.w = acc1[3] + xr[19] * sbuf[wb][lloc + 19];
        *(float4*)orow = o0;
        *(float4*)(orow + 16) = o1;
    }
}

extern "C" void kernel_launch(void* const* d_in, const int* in_sizes, int n_in,
                              void* d_out, int out_size, void* d_ws, size_t ws_size,
                              hipStream_t stream) {
    const float* v    = (const float*)d_in[0];
    const float* k    = (const float*)d_in[1];
    const float* bias = (const float*)d_in[2];
    const float* x1   = (const float*)d_in[3];
    const float* x2   = (const float*)d_in[4];
    float* out = (float*)d_out;

    const int D = in_sizes[2];            // 1024
    const int H = D / NHd;                // 128
    const int L = in_sizes[1] / H;        // 2048
    const int B = in_sizes[0] / (D * L);  // 2

    dim3 grid(H, L / 64);
    hyena_mfma5_kernel<<<grid, 256, 0, stream>>>(v, k, bias, x1, x2, out, B, H, L);
}

// Round 6
// 158.778 us; speedup vs baseline: 3.2522x; 1.1186x over previous
//
#include <hip/hip_runtime.h>
#include <stdint.h>

// Multi-head Hyena conv, MFMA flash-attention form, round 6:
//   S^T[m][l] = sum_d1 v[d1,m]*x1[d1,l]       mfma 16x16x32 (K=8 valid)
//   P[l][m]   = S * k[l-m]   (sliding f32x4 gate window, zero => causal)
//   O^T[d2][l] += x2 . P^T                    mfma 16x16x32 (full K=32)
// Round-6 change: mfma2 operands swapped (x2 = A, gated S packed IN REGISTERS
// as B with pi-permuted k-order baked into x2T layout) => the 4KB/unit P
// LDS round-trip is eliminated. Gate g10 carried across iterations (3->2
// gate reads/unit). LDS 30.7 -> 20.2 KB.
// Shapes fixed by setup: B=2, D=1024, L=2048, NH=8, H=128.

typedef __attribute__((ext_vector_type(8))) short bf16x8;
typedef __attribute__((ext_vector_type(4))) float f32x4;

#define NHd  8
#define SC   128     // m superchunk staged in LDS
#define GW   192     // gate window entries: l-m spans [l0b-s0-127, l0b-s0+63]

static __device__ __forceinline__ uint32_t pkbf(float a, float b) {
    // pack {bf16(a) lo, bf16(b) hi}; +0x8000 = round-to-nearest (ties away)
    const uint32_t ua = __float_as_uint(a) + 0x8000u;
    const uint32_t ub = __float_as_uint(b) + 0x8000u;
    return __builtin_amdgcn_perm(ub, ua, 0x07060302u);
}

union U8 { uint32_t u[4]; bf16x8 v; uint4 q; };

__global__ __launch_bounds__(256, 6) void hyena_mfma6_kernel(
    const float* __restrict__ v, const float* __restrict__ kf,
    const float* __restrict__ bias, const float* __restrict__ x1,
    const float* __restrict__ x2, float* __restrict__ out,
    int B, int H, int L)
{
    __shared__ __align__(16) float  ks[2048];           // raw k[h,:] prefix
    __shared__ __align__(16) float4 gwin[GW];           // sliding gate window
    __shared__ __align__(16) ushort vT[2][SC][NHd];     // [b][m][d1] bf16
    __shared__ __align__(16) ushort x2T[2][NHd][136];   // [b][d2][pi(m)] bf16
    __shared__ float sbuf[2][64];                       // skip gate per (b,l)

    const int tid  = threadIdx.x;
    const int h    = blockIdx.x;
    const int l0b  = ((int)gridDim.y - 1 - (int)blockIdx.y) * 64;  // big-l first
    const int nk   = l0b + 64;

    const int lane = tid & 63, wv = tid >> 6;
    const int lq   = lane & 15, quad = lane >> 4;
    const int wb   = wv >> 1;               // batch handled by this wave
    const int wl0  = l0b + (wv & 1) * 32;   // wave's 32-l range start
    const int baseb = (wb * H + h) * NHd * L;

    // ---------- prologue ----------
    for (int i = tid; i < nk; i += 256) ks[i] = kf[h * L + i];

    // xf fragments (mfma1 B operand) straight from global, packed in registers
    bf16x8 xf0 = {}, xf1 = {};
    if (quad == 0) {
        float a0[NHd], a1[NHd];
#pragma unroll
        for (int d1 = 0; d1 < NHd; ++d1) {
            a0[d1] = x1[baseb + d1 * L + wl0 + lq];
            a1[d1] = x1[baseb + d1 * L + wl0 + 16 + lq];
        }
        U8 u0, u1;
#pragma unroll
        for (int j = 0; j < 4; ++j) {
            u0.u[j] = pkbf(a0[2 * j], a0[2 * j + 1]);
            u1.u[j] = pkbf(a1[2 * j], a1[2 * j + 1]);
        }
        xf0 = u0.v; xf1 = u1.v;
    }

    // skip-term gate, both b (threads 0..127)
    if (tid < 128) {
        const int bb = tid >> 6, l = tid & 63;
        const int bs = (bb * H + h) * NHd * L;
        float s = 0.f;
#pragma unroll
        for (int d1 = 0; d1 < NHd; ++d1)
            s += bias[h * NHd + d1] * x1[bs + d1 * L + l0b + l]
                                    * v [bs + d1 * L + l0b + l];
        sbuf[bb][l] = s;
    }

    f32x4 acc0 = {0.f, 0.f, 0.f, 0.f}, acc1 = {0.f, 0.f, 0.f, 0.f};
    const int wlmax = wl0 + 31;
    // in-loop gate window coordinate (s0-independent): e = ebase - c (+/-16)
    const int ebase = 127 + (wv & 1) * 32 + lq - 4 * quad;

    bool gfirst = true;
    float4 g10c = {0.f, 0.f, 0.f, 0.f};    // carried: g10(c+32) == g01(c)

    for (int s0 = 0; s0 < nk; s0 += SC) {
        __syncthreads();   // protects gwin/vT/x2T from previous iter's readers
        {   // stage vT [b][m][d1] and x2T [b][d2][pi(m)], bf16 via pkbf
            const int bb = tid >> 7, row = tid & 127;
            const int bs = (bb * H + h) * NHd * L;
            const float* vp = v + bs + s0 + row;
            float f[NHd];
#pragma unroll
            for (int d1 = 0; d1 < NHd; ++d1) f[d1] = vp[d1 * L];
            *(uint4*)&vT[bb][row][0] = make_uint4(
                pkbf(f[0], f[1]), pkbf(f[2], f[3]),
                pkbf(f[4], f[5]), pkbf(f[6], f[7]));

            // x2T in pi-permuted order: within each 32-m group, value at m
            // goes to pos 8*((m&15)>>2) + (m&3) + 4*(m>>4)
            const int d2 = row >> 4, ms = (row & 15) * 8;
            const int G = ms & ~31;                       // 32-group base
            const int o = ms & 31;                        // 0,8,16,24
            const int pa = ((o >> 2) & 3) * 8 + (o >> 4) * 4;
            const float* xp = x2 + bs + d2 * L + s0 + ms;
            const float4 q0 = *(const float4*)xp;
            const float4 q1 = *(const float4*)(xp + 4);
            *(uint2*)&x2T[bb][d2][G + pa] =
                make_uint2(pkbf(q0.x, q0.y), pkbf(q0.z, q0.w));
            *(uint2*)&x2T[bb][d2][G + pa + 8] =
                make_uint2(pkbf(q1.x, q1.y), pkbf(q1.z, q1.w));
        }
        // rebuild sliding gate window: gwin[e] = {k[i],k[i-1],k[i-2],k[i-3]},
        // i = l0b - s0 - 127 + e; i<0 components -> 0 (causality)
        if (tid < GW - 1) {
            const int i = l0b - s0 - 127 + tid;
            float4 w = {0.f, 0.f, 0.f, 0.f};
            if (i >= 3) {
                w.x = ks[i]; w.y = ks[i - 1]; w.z = ks[i - 2]; w.w = ks[i - 3];
            } else if (i >= 0) {
                w.x = ks[i];
                if (i >= 1) w.y = ks[i - 1];
                if (i >= 2) w.z = ks[i - 2];
            }
            gwin[tid] = w;
        }
        __syncthreads();

        const int cmax = min(SC, wlmax - s0 + 1);   // wave-uniform, mult of 32
        for (int c = 0; c < cmax; c += 32) {
            // ---- loads first (independent) ----
            bf16x8 av0 = {}, av1 = {};
            if (quad == 0) {
                av0 = *(const bf16x8*)&vT[wb][c + lq][0];
                av1 = *(const bf16x8*)&vT[wb][c + 16 + lq][0];
            }
            const int ge = ebase - c;
            float4 g10;
            if (gfirst) { g10 = *(const float4*)&gwin[ge + 16]; gfirst = false; }
            else        g10 = g10c;
            const float4 g00 = *(const float4*)&gwin[ge];        // S00 & S11
            const float4 g01 = *(const float4*)&gwin[ge - 16];   // S01
            g10c = g01;                                          // next iter's g10
            // mfma2 A operand: x2 in pi-permuted k-order (same addr as old bx)
            const bf16x8 ax = *(const bf16x8*)&x2T[wb][lq & 7][c + 8 * quad];

            // ---- mfma1 x4: S^T, 2 m-chunks x 2 l-subtiles ----
            const f32x4 Z = {0.f, 0.f, 0.f, 0.f};
            const f32x4 S00 = __builtin_amdgcn_mfma_f32_16x16x32_bf16(av0, xf0, Z, 0, 0, 0);
            const f32x4 S01 = __builtin_amdgcn_mfma_f32_16x16x32_bf16(av1, xf0, Z, 0, 0, 0);
            const f32x4 S10 = __builtin_amdgcn_mfma_f32_16x16x32_bf16(av0, xf1, Z, 0, 0, 0);
            const f32x4 S11 = __builtin_amdgcn_mfma_f32_16x16x32_bf16(av1, xf1, Z, 0, 0, 0);

            // ---- gate + pack B-frags IN REGISTERS (no LDS round-trip) ----
            // B k-slot (quad,j): j<4 -> chunk c (S00/S10), j>=4 -> chunk c+16
            U8 p0, p1;
            p0.u[0] = pkbf(S00[0] * g00.x, S00[1] * g00.y);
            p0.u[1] = pkbf(S00[2] * g00.z, S00[3] * g00.w);
            p0.u[2] = pkbf(S01[0] * g01.x, S01[1] * g01.y);
            p0.u[3] = pkbf(S01[2] * g01.z, S01[3] * g01.w);
            p1.u[0] = pkbf(S10[0] * g10.x, S10[1] * g10.y);
            p1.u[1] = pkbf(S10[2] * g10.z, S10[3] * g10.w);
            p1.u[2] = pkbf(S11[0] * g00.x, S11[1] * g00.y);
            p1.u[3] = pkbf(S11[2] * g00.z, S11[3] * g00.w);

            // ---- mfma2: O^T += x2 . P^T, full K=32 ----
            acc0 = __builtin_amdgcn_mfma_f32_16x16x32_bf16(ax, p0.v, acc0, 0, 0, 0);
            acc1 = __builtin_amdgcn_mfma_f32_16x16x32_bf16(ax, p1.v, acc1, 0, 0, 0);
        }
    }

    // ---------- epilogue: O^T layout: lane (quad,lq): d2 = 4*quad+r, l = lq ----
    if (quad < 2) {
        const int d2b = 4 * quad;
        const int lA  = wl0 + lq;                 // subtile-0 l; subtile-1 = +16
        const float sb0 = sbuf[wb][(wv & 1) * 32 + lq];
        const float sb1 = sbuf[wb][(wv & 1) * 32 + 16 + lq];
#pragma unroll
        for (int r = 0; r < 4; ++r) {
            const int ro = baseb + (d2b + r) * L + lA;
            out[ro]      = acc0[r] + x2[ro]      * sb0;
            out[ro + 16] = acc1[r] + x2[ro + 16] * sb1;
        }
    }
}

extern "C" void kernel_launch(void* const* d_in, const int* in_sizes, int n_in,
                              void* d_out, int out_size, void* d_ws, size_t ws_size,
                              hipStream_t stream) {
    const float* v    = (const float*)d_in[0];
    const float* k    = (const float*)d_in[1];
    const float* bias = (const float*)d_in[2];
    const float* x1   = (const float*)d_in[3];
    const float* x2   = (const float*)d_in[4];
    float* out = (float*)d_out;

    const int D = in_sizes[2];            // 1024
    const int H = D / NHd;                // 128
    const int L = in_sizes[1] / H;        // 2048
    const int B = in_sizes[0] / (D * L);  // 2

    dim3 grid(H, L / 64);
    hyena_mfma6_kernel<<<grid, 256, 0, stream>>>(v, k, bias, x1, x2, out, B, H, L);
}